// Round 10
// baseline (163.955 us; speedup 1.0000x reference)
//
#include <hip/hip_runtime.h>
#include <math.h>

#define LSEQ 128
#define NLL 16384      // L*L
#define NBATCH 4
#define DIM 768
#define NB 4
#define ALPHA_C 32.0f
#define MRG_C 0.05f
#define CLW_C 0.05f
#define BPB 512        // blocks per batch per table (2048/4)

__device__ __forceinline__ float wave_reduce_f(float v) {
#pragma unroll
    for (int s = 1; s < 64; s <<= 1) v += __shfl_xor(v, s);
    return v;
}

__device__ __forceinline__ float dot4(float4 a, float4 b) {
    return a.x*b.x + a.y*b.y + a.z*b.z + a.w*b.w;
}

// volatile LDS read: keeps wS/wE OUT of registers (no hoist -> no pressure)
__device__ __forceinline__ float4 ldsv4(const float* p) {
    const volatile float* q = p;
    return make_float4(q[0], q[1], q[2], q[3]);
}

// Wave-per-row (64 lanes x float4 = 1KB per chunk, 3 chunks/row), 8 rows/wave.
// Register budget pinned at senti level (~75): proxies in regs; edge's wS/wE
// live in LDS and are re-read per row (volatile). Full butterfly + lane==rr
// register stash; batched transcendental epilogue on lanes 0-7.
template<bool EDGE>
__device__ __forceinline__ void pass_body(
    const float* __restrict__ table, const int* __restrict__ labels,
    const int* __restrict__ attn, const float* __restrict__ prox,
    const float* __restrict__ bS, const float* __restrict__ bE,
    const int* __restrict__ tlabS, const int* __restrict__ tlabE,
    float* __restrict__ pS, float* __restrict__ pE,
    float* __restrict__ partial, const float* __restrict__ wlds,
    float* __restrict__ sacc_all, int g, int wib, int lane, int tid)
{
    const int b = g >> 9;                // batch
    const int wave_row0 = g*32 + wib*8;  // this wave's 8 rows

    // lens[b]
    int lens_i = attn[b*LSEQ + lane] + attn[b*LSEQ + 64 + lane];
#pragma unroll
    for (int s = 1; s < 64; s <<= 1) lens_i += __shfl_xor(lens_i, s);

    // ---- proxies in named registers: this lane's 12-float slice ----
    const int lo4 = lane * 4;
    const float4 p00 = *(const float4*)(prox + 0*DIM +   0 + lo4);
    const float4 p01 = *(const float4*)(prox + 0*DIM + 256 + lo4);
    const float4 p02 = *(const float4*)(prox + 0*DIM + 512 + lo4);
    const float4 p10 = *(const float4*)(prox + 1*DIM +   0 + lo4);
    const float4 p11 = *(const float4*)(prox + 1*DIM + 256 + lo4);
    const float4 p12 = *(const float4*)(prox + 1*DIM + 512 + lo4);
    const float4 p20 = *(const float4*)(prox + 2*DIM +   0 + lo4);
    const float4 p21 = *(const float4*)(prox + 2*DIM + 256 + lo4);
    const float4 p22 = *(const float4*)(prox + 2*DIM + 512 + lo4);
    const float4 p30 = *(const float4*)(prox + 3*DIM +   0 + lo4);
    const float4 p31 = *(const float4*)(prox + 3*DIM + 256 + lo4);
    const float4 p32 = *(const float4*)(prox + 3*DIM + 512 + lo4);
    float pinv0, pinv1, pinv2, pinv3;
    {
        float s0 = dot4(p00,p00)+dot4(p01,p01)+dot4(p02,p02);
        float s1 = dot4(p10,p10)+dot4(p11,p11)+dot4(p12,p12);
        float s2 = dot4(p20,p20)+dot4(p21,p21)+dot4(p22,p22);
        float s3 = dot4(p30,p30)+dot4(p31,p31)+dot4(p32,p32);
        s0 = wave_reduce_f(s0); s1 = wave_reduce_f(s1);
        s2 = wave_reduce_f(s2); s3 = wave_reduce_f(s3);
        pinv0 = 1.0f / fmaxf(sqrtf(s0), 1e-12f);
        pinv1 = 1.0f / fmaxf(sqrtf(s1), 1e-12f);
        pinv2 = 1.0f / fmaxf(sqrtf(s2), 1e-12f);
        pinv3 = 1.0f / fmaxf(sqrtf(s3), 1e-12f);
    }

    const float* rowp = table + (size_t)wave_row0 * DIM + lo4;

    // per-row register stash: lane rr keeps row rr's reduced values
    float s_xx=0, s_d0=0, s_d1=0, s_d2=0, s_d3=0, s_dS=0, s_dE=0;

    // ---------- hot loop: 8 rows ----------
#pragma unroll 1
    for (int rr = 0; rr < 8; ++rr) {
        const float* xb = rowp + rr*DIM;
        const float4 x0 = *(const float4*)(xb);
        const float4 x1 = *(const float4*)(xb + 256);
        const float4 x2 = *(const float4*)(xb + 512);
        float xx = dot4(x0,x0) + dot4(x1,x1) + dot4(x2,x2);
        float d0 = dot4(x0,p00) + dot4(x1,p01) + dot4(x2,p02);
        float d1 = dot4(x0,p10) + dot4(x1,p11) + dot4(x2,p12);
        float d2 = dot4(x0,p20) + dot4(x1,p21) + dot4(x2,p22);
        float d3 = dot4(x0,p30) + dot4(x1,p31) + dot4(x2,p32);
        float dS, dE;
        if constexpr (EDGE) {
            dS = dot4(x0, ldsv4(wlds +   0 + lo4))
               + dot4(x1, ldsv4(wlds + 256 + lo4))
               + dot4(x2, ldsv4(wlds + 512 + lo4));
            dE = dot4(x0, ldsv4(wlds + DIM +   0 + lo4))
               + dot4(x1, ldsv4(wlds + DIM + 256 + lo4))
               + dot4(x2, ldsv4(wlds + DIM + 512 + lo4));
        }
        // full butterfly: every lane ends with the row sum
#pragma unroll
        for (int s = 1; s < 64; s <<= 1) {
            xx += __shfl_xor(xx, s);
            d0 += __shfl_xor(d0, s); d1 += __shfl_xor(d1, s);
            d2 += __shfl_xor(d2, s); d3 += __shfl_xor(d3, s);
            if constexpr (EDGE) { dS += __shfl_xor(dS, s); dE += __shfl_xor(dE, s); }
        }
        if (lane == rr) {
            s_xx = xx; s_d0 = d0; s_d1 = d1; s_d2 = d2; s_d3 = d3;
            if constexpr (EDGE) { s_dS = dS; s_dE = dE; }
        }
    }

    // ---------- cold epilogue: lanes 0..7 handle the wave's 8 rows ----------
    float Pa0=0,Pa1=0,Pa2=0,Pa3=0, Na0=0,Na1=0,Na2=0,Na3=0, Ca0=0,Ca1=0,Ca2=0,Ca3=0;
    float sBS = 0.f, sBE = 0.f;
    if (lane < 8) {
        const int r = wave_row0 + lane;
        const int i = r & (NLL - 1);
        const int l = i >> 7, m = i & (LSEQ - 1);
        const bool valid = (l >= 1) && (l < lens_i - 1) && (m >= 1) && (m < lens_i - 1);
        if (valid) {
            const int lab = labels[r];
            const float xinv = 1.0f / fmaxf(sqrtf(s_xx), 1e-12f);
            const float c0 = s_d0 * xinv * pinv0;
            const float c1 = s_d1 * xinv * pinv1;
            const float c2 = s_d2 * xinv * pinv2;
            const float c3 = s_d3 * xinv * pinv3;
            if (lab == 0) { Pa0 = expf(-ALPHA_C*(c0 - MRG_C)); Ca0 = 1.f; }
            else          { Na0 = expf( ALPHA_C*(c0 + MRG_C)); }
            if (lab == 1) { Pa1 = expf(-ALPHA_C*(c1 - MRG_C)); Ca1 = 1.f; }
            else          { Na1 = expf( ALPHA_C*(c1 + MRG_C)); }
            if (lab == 2) { Pa2 = expf(-ALPHA_C*(c2 - MRG_C)); Ca2 = 1.f; }
            else          { Na2 = expf( ALPHA_C*(c2 + MRG_C)); }
            if (lab == 3) { Pa3 = expf(-ALPHA_C*(c3 - MRG_C)); Ca3 = 1.f; }
            else          { Na3 = expf( ALPHA_C*(c3 + MRG_C)); }
        }
        if constexpr (EDGE) {
            const float xSl = s_dS + bS[0], xEl = s_dE + bE[0];
            const int ls = tlabS[r], le = tlabE[r];
            const float w = (ls >= 0) ? 1.f : 0.f;
            const float spS = fmaxf(xSl, 0.f) + log1pf(expf(-fabsf(xSl)));
            const float spE = fmaxf(xEl, 0.f) + log1pf(expf(-fabsf(xEl)));
            sBS = w * (spS - xSl * (float)ls);
            sBE = w * (spE - xEl * (float)le);
            pS[r] = w / (1.f + expf(-xSl));
            pE[r] = w / (1.f + expf(-xEl));
        }
    }
    // reduce 14 accumulators over lanes 0..7 (zeros elsewhere; xor<8 stays in-group)
#pragma unroll
    for (int s = 1; s < 8; s <<= 1) {
        Pa0 += __shfl_xor(Pa0, s); Pa1 += __shfl_xor(Pa1, s);
        Pa2 += __shfl_xor(Pa2, s); Pa3 += __shfl_xor(Pa3, s);
        Na0 += __shfl_xor(Na0, s); Na1 += __shfl_xor(Na1, s);
        Na2 += __shfl_xor(Na2, s); Na3 += __shfl_xor(Na3, s);
        Ca0 += __shfl_xor(Ca0, s); Ca1 += __shfl_xor(Ca1, s);
        Ca2 += __shfl_xor(Ca2, s); Ca3 += __shfl_xor(Ca3, s);
        sBS += __shfl_xor(sBS, s); sBE += __shfl_xor(sBE, s);
    }
    if (lane == 0) {
        float* sp = sacc_all + wib*14;
        sp[0]=Pa0; sp[1]=Pa1; sp[2]=Pa2; sp[3]=Pa3;
        sp[4]=Na0; sp[5]=Na1; sp[6]=Na2; sp[7]=Na3;
        sp[8]=Ca0; sp[9]=Ca1; sp[10]=Ca2; sp[11]=Ca3;
        sp[12]=sBS; sp[13]=sBE;
    }
    __syncthreads();
    if (tid < 14) {
        const float s = sacc_all[0*14+tid] + sacc_all[1*14+tid]
                      + sacc_all[2*14+tid] + sacc_all[3*14+tid];
        const int blk = g & (BPB - 1);
        partial[(b * 14 + tid) * BPB + blk] = s;
    }
}

// grid 4096: tbl = bid&1 (block-uniform), g = bid>>1 in [0,2048), 32 rows/block.
__global__ __launch_bounds__(256)
void fused_pass(const float* __restrict__ tabE, const float* __restrict__ tabS,
                const int* __restrict__ labE, const int* __restrict__ labSen,
                const int* __restrict__ attn,
                const float* __restrict__ proxE, const float* __restrict__ proxSen,
                const float* __restrict__ wS, const float* __restrict__ bS,
                const float* __restrict__ wE, const float* __restrict__ bE,
                const int* __restrict__ tlabS, const int* __restrict__ tlabE,
                float* __restrict__ pS, float* __restrict__ pE,
                float* __restrict__ partE, float* __restrict__ partSen)
{
    __shared__ float wlds[2*DIM];   // wS | wE (edge blocks only)
    __shared__ float sacc[4*14];
    const int tid = threadIdx.x, wib = tid >> 6, lane = tid & 63;
    const int tbl = blockIdx.x & 1;
    const int g = blockIdx.x >> 1;
    if (tbl == 0) {
        for (int i = tid; i < 384; i += 256) {
            const float* src = (i < 192) ? (wS + i*4) : (wE + (i-192)*4);
            *reinterpret_cast<float4*>(&wlds[i*4]) = *reinterpret_cast<const float4*>(src);
        }
        __syncthreads();
        pass_body<true >(tabE, labE, attn, proxE, bS, bE, tlabS, tlabE,
                         pS, pE, partE, wlds, sacc, g, wib, lane, tid);
    } else {
        __syncthreads();
        pass_body<false>(tabS, labSen, attn, proxSen, nullptr, nullptr,
                         nullptr, nullptr, nullptr, nullptr, partSen, wlds, sacc,
                         g, wib, lane, tid);
    }
}

// 10 blocks: 0-7 = prune (exact k-th largest), 8-9 = finalize (scalar outputs).
__global__ __launch_bounds__(1024)
void tail_k(const float* __restrict__ pS, const float* __restrict__ pE,
            const int* __restrict__ attn,
            const float* __restrict__ partE, const float* __restrict__ partS,
            float* __restrict__ out)
{
    __shared__ unsigned sh[NLL];     // 64 KB (prune path)
    __shared__ int csum[16];
    __shared__ float gg[56];
    const int tid = threadIdx.x, wave = tid >> 6, lane = tid & 63;

    if (blockIdx.x >= 8) {
        const int tbl = blockIdx.x - 8;
        const float* part = (tbl == 0) ? partE : partS;
        for (int grp = wave; grp < 56; grp += 16) {
            float s = 0.f;
#pragma unroll
            for (int j = lane; j < BPB; j += 64) s += part[grp*BPB + j];
            s = wave_reduce_f(s);
            if (lane == 0) gg[grp] = s;
        }
        __syncthreads();
        if (tid == 0) {
            float tot = 0.f;
            for (int b = 0; b < NBATCH; ++b) {
                const float* G = gg + b * 14;
                int nv = 0;
                for (int c = 0; c < NB; ++c) nv += (G[8+c] > 0.f) ? 1 : 0;
                const float nvf = (float)((nv > 1) ? nv : 1);
                float pos = 0.f, neg = 0.f;
                for (int c = 0; c < NB; ++c) { pos += log1pf(G[c]); neg += log1pf(G[4+c]); }
                tot += pos / nvf + neg * 0.25f;
            }
            out[tbl] = CLW_C * tot * 0.25f;
            if (tbl == 0) {
                float bs = 0.f, be = 0.f;
                for (int b = 0; b < NBATCH; ++b) { bs += gg[b*14 + 12]; be += gg[b*14 + 13]; }
                out[2] = bs * (1.0f / 65536.0f);
                out[3] = be * (1.0f / 65536.0f);
            }
        }
        return;
    }

    const int a = blockIdx.x >> 2;   // 0 = S, 1 = E
    const int b = blockIdx.x & 3;
    const float* p = (a ? pE : pS) + (size_t)b * NLL;
    float* o = out + 4 + (size_t)a * (NBATCH * NLL) + (size_t)b * NLL;

    int asum = attn[b*LSEQ + lane] + attn[b*LSEQ + 64 + lane];
#pragma unroll
    for (int s = 1; s < 64; s <<= 1) asum += __shfl_xor(asum, s);
    const int mask_len = asum - 2;
    int k = (int)((float)mask_len * 0.3f);
    k = (k > 10) ? k : 10;
    const int ml2 = mask_len * mask_len;
    k = (k < ml2) ? k : ml2;

    for (int j = tid; j < NLL; j += 1024) sh[j] = __float_as_uint(p[j]);
    __syncthreads();

    unsigned lo = 0u, hi = 0x3F800000u;   // p in [0,1] -> bits <= 0x3F800000
    for (int it = 0; it < 32; ++it) {
        if (lo >= hi) break;                       // uniform across block
        const unsigned span = hi - lo;
        const unsigned mid = lo + (span >> 1) + (span & 1u);   // ceil midpoint, > lo
        int c = 0;
        for (int j = tid; j < NLL; j += 1024) c += (sh[j] >= mid) ? 1 : 0;
#pragma unroll
        for (int s = 1; s < 64; s <<= 1) c += __shfl_xor(c, s);
        if (lane == 0) csum[wave] = c;
        __syncthreads();
        int tot = 0;
#pragma unroll
        for (int w = 0; w < 16; ++w) tot += csum[w];
        if (tot >= k) lo = mid; else hi = mid - 1u;
        __syncthreads();
    }

    for (int j = tid; j < NLL; j += 1024) o[j] = (sh[j] >= lo) ? 1.0f : 0.0f;
}

extern "C" void kernel_launch(void* const* d_in, const int* in_sizes, int n_in,
                              void* d_out, int out_size, void* d_ws, size_t ws_size,
                              hipStream_t stream)
{
    const float* table_edge  = (const float*)d_in[0];
    const float* table_senti = (const float*)d_in[1];
    const int*   attn        = (const int*)d_in[2];
    const int*   tlabS       = (const int*)d_in[3];
    const int*   tlabE       = (const int*)d_in[4];
    const int*   lab_edge    = (const int*)d_in[5];
    const int*   lab_senti   = (const int*)d_in[6];
    const float* prox_edge   = (const float*)d_in[7];
    const float* prox_senti  = (const float*)d_in[8];
    const float* w_S         = (const float*)d_in[9];
    const float* b_S         = (const float*)d_in[10];
    const float* w_E         = (const float*)d_in[11];
    const float* b_E         = (const float*)d_in[12];

    float* out   = (float*)d_out;
    float* ws    = (float*)d_ws;
    float* pS    = ws;                      // 65536
    float* pE    = ws + 65536;              // 65536
    float* partE = ws + 131072;             // 4*14*512 = 28672
    float* partS = partE + 28672;           // 28672

    fused_pass<<<4096, 256, 0, stream>>>(table_edge, table_senti,
        lab_edge, lab_senti, attn, prox_edge, prox_senti,
        w_S, b_S, w_E, b_E, tlabS, tlabE, pS, pE, partE, partS);
    tail_k<<<10, 1024, 0, stream>>>(pS, pE, attn, partE, partS, out);
}

// Round 11
// 122.627 us; speedup vs baseline: 1.3370x; 1.3370x over previous
//
#include <hip/hip_runtime.h>
#include <math.h>

#define LSEQ 128
#define NLL 16384      // L*L
#define NBATCH 4
#define DIM 768
#define NB 4
#define ALPHA_C 32.0f
#define MRG_C 0.05f
#define CLW_C 0.05f
#define BPB 512        // blocks per batch per table (2048/4)

__device__ __forceinline__ float wave_reduce_f(float v) {
#pragma unroll
    for (int s = 1; s < 64; s <<= 1) v += __shfl_xor(v, s);
    return v;
}

__device__ __forceinline__ float dot4(float4 a, float4 b) {
    return a.x*b.x + a.y*b.y + a.z*b.z + a.w*b.w;
}

// Wave-per-row (64 lanes x float4 = 1KB per chunk, 3 chunks/row), 8 rows/wave.
// Proxies resident in registers (48 VGPR, senti-proven). Edge's wS/wE are NOT
// kept resident: re-loaded per chunk from L1 (6KB, L1-resident) with
// sched_barrier(0) fences so only 8 transient regs live -> no spill.
// Full butterfly + lane==rr stash; batched transcendental epilogue on lanes 0-7.
template<bool EDGE>
__device__ __forceinline__ void pass_body(
    const float* __restrict__ table, const int* __restrict__ labels,
    const int* __restrict__ attn, const float* __restrict__ prox,
    const float* __restrict__ wS, const float* __restrict__ bS,
    const float* __restrict__ wE, const float* __restrict__ bE,
    const int* __restrict__ tlabS, const int* __restrict__ tlabE,
    float* __restrict__ pS, float* __restrict__ pE,
    float* __restrict__ partial, float* __restrict__ sacc_all,
    int g, int wib, int lane, int tid)
{
    const int b = g >> 9;                // batch
    const int wave_row0 = g*32 + wib*8;  // this wave's 8 rows

    // lens[b]
    int lens_i = attn[b*LSEQ + lane] + attn[b*LSEQ + 64 + lane];
#pragma unroll
    for (int s = 1; s < 64; s <<= 1) lens_i += __shfl_xor(lens_i, s);

    // ---- proxies in named registers: this lane's 12-float slice ----
    const int lo4 = lane * 4;
    const float4 p00 = *(const float4*)(prox + 0*DIM +   0 + lo4);
    const float4 p01 = *(const float4*)(prox + 0*DIM + 256 + lo4);
    const float4 p02 = *(const float4*)(prox + 0*DIM + 512 + lo4);
    const float4 p10 = *(const float4*)(prox + 1*DIM +   0 + lo4);
    const float4 p11 = *(const float4*)(prox + 1*DIM + 256 + lo4);
    const float4 p12 = *(const float4*)(prox + 1*DIM + 512 + lo4);
    const float4 p20 = *(const float4*)(prox + 2*DIM +   0 + lo4);
    const float4 p21 = *(const float4*)(prox + 2*DIM + 256 + lo4);
    const float4 p22 = *(const float4*)(prox + 2*DIM + 512 + lo4);
    const float4 p30 = *(const float4*)(prox + 3*DIM +   0 + lo4);
    const float4 p31 = *(const float4*)(prox + 3*DIM + 256 + lo4);
    const float4 p32 = *(const float4*)(prox + 3*DIM + 512 + lo4);
    float pinv0, pinv1, pinv2, pinv3;
    {
        float s0 = dot4(p00,p00)+dot4(p01,p01)+dot4(p02,p02);
        float s1 = dot4(p10,p10)+dot4(p11,p11)+dot4(p12,p12);
        float s2 = dot4(p20,p20)+dot4(p21,p21)+dot4(p22,p22);
        float s3 = dot4(p30,p30)+dot4(p31,p31)+dot4(p32,p32);
        s0 = wave_reduce_f(s0); s1 = wave_reduce_f(s1);
        s2 = wave_reduce_f(s2); s3 = wave_reduce_f(s3);
        pinv0 = 1.0f / fmaxf(sqrtf(s0), 1e-12f);
        pinv1 = 1.0f / fmaxf(sqrtf(s1), 1e-12f);
        pinv2 = 1.0f / fmaxf(sqrtf(s2), 1e-12f);
        pinv3 = 1.0f / fmaxf(sqrtf(s3), 1e-12f);
    }

    const float* rowp = table + (size_t)wave_row0 * DIM + lo4;

    // per-row register stash: lane rr keeps row rr's reduced values
    float s_xx=0, s_d0=0, s_d1=0, s_d2=0, s_d3=0, s_dS=0, s_dE=0;

    // ---------- hot loop: 8 rows ----------
#pragma unroll 1
    for (int rr = 0; rr < 8; ++rr) {
        const float* xb = rowp + rr*DIM;
        const float4 x0 = *(const float4*)(xb);
        const float4 x1 = *(const float4*)(xb + 256);
        const float4 x2 = *(const float4*)(xb + 512);
        float xx = dot4(x0,x0) + dot4(x1,x1) + dot4(x2,x2);
        float d0 = dot4(x0,p00) + dot4(x1,p01) + dot4(x2,p02);
        float d1 = dot4(x0,p10) + dot4(x1,p11) + dot4(x2,p12);
        float d2 = dot4(x0,p20) + dot4(x1,p21) + dot4(x2,p22);
        float d3 = dot4(x0,p30) + dot4(x1,p31) + dot4(x2,p32);
        float dS = 0.f, dE = 0.f;
        if constexpr (EDGE) {
            // stream wS/wE from L1 chunk-by-chunk; fences keep <=2 loads live
            __builtin_amdgcn_sched_barrier(0);
            {
                float4 wa = *(const float4*)(wS +   0 + lo4);
                float4 wb = *(const float4*)(wE +   0 + lo4);
                dS += dot4(x0, wa); dE += dot4(x0, wb);
            }
            __builtin_amdgcn_sched_barrier(0);
            {
                float4 wa = *(const float4*)(wS + 256 + lo4);
                float4 wb = *(const float4*)(wE + 256 + lo4);
                dS += dot4(x1, wa); dE += dot4(x1, wb);
            }
            __builtin_amdgcn_sched_barrier(0);
            {
                float4 wa = *(const float4*)(wS + 512 + lo4);
                float4 wb = *(const float4*)(wE + 512 + lo4);
                dS += dot4(x2, wa); dE += dot4(x2, wb);
            }
            __builtin_amdgcn_sched_barrier(0);
        }
        // full butterfly: every lane ends with the row sum
#pragma unroll
        for (int s = 1; s < 64; s <<= 1) {
            xx += __shfl_xor(xx, s);
            d0 += __shfl_xor(d0, s); d1 += __shfl_xor(d1, s);
            d2 += __shfl_xor(d2, s); d3 += __shfl_xor(d3, s);
            if constexpr (EDGE) { dS += __shfl_xor(dS, s); dE += __shfl_xor(dE, s); }
        }
        if (lane == rr) {
            s_xx = xx; s_d0 = d0; s_d1 = d1; s_d2 = d2; s_d3 = d3;
            if constexpr (EDGE) { s_dS = dS; s_dE = dE; }
        }
    }

    // ---------- cold epilogue: lanes 0..7 handle the wave's 8 rows ----------
    float Pa0=0,Pa1=0,Pa2=0,Pa3=0, Na0=0,Na1=0,Na2=0,Na3=0, Ca0=0,Ca1=0,Ca2=0,Ca3=0;
    float sBS = 0.f, sBE = 0.f;
    if (lane < 8) {
        const int r = wave_row0 + lane;
        const int i = r & (NLL - 1);
        const int l = i >> 7, m = i & (LSEQ - 1);
        const bool valid = (l >= 1) && (l < lens_i - 1) && (m >= 1) && (m < lens_i - 1);
        if (valid) {
            const int lab = labels[r];
            const float xinv = 1.0f / fmaxf(sqrtf(s_xx), 1e-12f);
            const float c0 = s_d0 * xinv * pinv0;
            const float c1 = s_d1 * xinv * pinv1;
            const float c2 = s_d2 * xinv * pinv2;
            const float c3 = s_d3 * xinv * pinv3;
            if (lab == 0) { Pa0 = expf(-ALPHA_C*(c0 - MRG_C)); Ca0 = 1.f; }
            else          { Na0 = expf( ALPHA_C*(c0 + MRG_C)); }
            if (lab == 1) { Pa1 = expf(-ALPHA_C*(c1 - MRG_C)); Ca1 = 1.f; }
            else          { Na1 = expf( ALPHA_C*(c1 + MRG_C)); }
            if (lab == 2) { Pa2 = expf(-ALPHA_C*(c2 - MRG_C)); Ca2 = 1.f; }
            else          { Na2 = expf( ALPHA_C*(c2 + MRG_C)); }
            if (lab == 3) { Pa3 = expf(-ALPHA_C*(c3 - MRG_C)); Ca3 = 1.f; }
            else          { Na3 = expf( ALPHA_C*(c3 + MRG_C)); }
        }
        if constexpr (EDGE) {
            const float xSl = s_dS + bS[0], xEl = s_dE + bE[0];
            const int ls = tlabS[r], le = tlabE[r];
            const float w = (ls >= 0) ? 1.f : 0.f;
            const float spS = fmaxf(xSl, 0.f) + log1pf(expf(-fabsf(xSl)));
            const float spE = fmaxf(xEl, 0.f) + log1pf(expf(-fabsf(xEl)));
            sBS = w * (spS - xSl * (float)ls);
            sBE = w * (spE - xEl * (float)le);
            pS[r] = w / (1.f + expf(-xSl));
            pE[r] = w / (1.f + expf(-xEl));
        }
    }
    // reduce 14 accumulators over lanes 0..7 (zeros elsewhere; xor<8 stays in-group)
#pragma unroll
    for (int s = 1; s < 8; s <<= 1) {
        Pa0 += __shfl_xor(Pa0, s); Pa1 += __shfl_xor(Pa1, s);
        Pa2 += __shfl_xor(Pa2, s); Pa3 += __shfl_xor(Pa3, s);
        Na0 += __shfl_xor(Na0, s); Na1 += __shfl_xor(Na1, s);
        Na2 += __shfl_xor(Na2, s); Na3 += __shfl_xor(Na3, s);
        Ca0 += __shfl_xor(Ca0, s); Ca1 += __shfl_xor(Ca1, s);
        Ca2 += __shfl_xor(Ca2, s); Ca3 += __shfl_xor(Ca3, s);
        sBS += __shfl_xor(sBS, s); sBE += __shfl_xor(sBE, s);
    }
    if (lane == 0) {
        float* sp = sacc_all + wib*14;
        sp[0]=Pa0; sp[1]=Pa1; sp[2]=Pa2; sp[3]=Pa3;
        sp[4]=Na0; sp[5]=Na1; sp[6]=Na2; sp[7]=Na3;
        sp[8]=Ca0; sp[9]=Ca1; sp[10]=Ca2; sp[11]=Ca3;
        sp[12]=sBS; sp[13]=sBE;
    }
    __syncthreads();
    if (tid < 14) {
        const float s = sacc_all[0*14+tid] + sacc_all[1*14+tid]
                      + sacc_all[2*14+tid] + sacc_all[3*14+tid];
        const int blk = g & (BPB - 1);
        partial[(b * 14 + tid) * BPB + blk] = s;
    }
}

// grid 4096: tbl = bid&1 (block-uniform), g = bid>>1 in [0,2048), 32 rows/block.
__global__ __launch_bounds__(256)
void fused_pass(const float* __restrict__ tabE, const float* __restrict__ tabS,
                const int* __restrict__ labE, const int* __restrict__ labSen,
                const int* __restrict__ attn,
                const float* __restrict__ proxE, const float* __restrict__ proxSen,
                const float* __restrict__ wS, const float* __restrict__ bS,
                const float* __restrict__ wE, const float* __restrict__ bE,
                const int* __restrict__ tlabS, const int* __restrict__ tlabE,
                float* __restrict__ pS, float* __restrict__ pE,
                float* __restrict__ partE, float* __restrict__ partSen)
{
    __shared__ float sacc[4*14];
    const int tid = threadIdx.x, wib = tid >> 6, lane = tid & 63;
    const int tbl = blockIdx.x & 1;
    const int g = blockIdx.x >> 1;
    if (tbl == 0)
        pass_body<true >(tabE, labE, attn, proxE, wS, bS, wE, bE, tlabS, tlabE,
                         pS, pE, partE, sacc, g, wib, lane, tid);
    else
        pass_body<false>(tabS, labSen, attn, proxSen, nullptr, nullptr, nullptr, nullptr,
                         nullptr, nullptr, nullptr, nullptr, partSen, sacc,
                         g, wib, lane, tid);
}

// 10 blocks: 0-7 = prune (exact k-th largest), 8-9 = finalize (scalar outputs).
__global__ __launch_bounds__(1024)
void tail_k(const float* __restrict__ pS, const float* __restrict__ pE,
            const int* __restrict__ attn,
            const float* __restrict__ partE, const float* __restrict__ partS,
            float* __restrict__ out)
{
    __shared__ unsigned sh[NLL];     // 64 KB (prune path)
    __shared__ int csum[16];
    __shared__ float gg[56];
    const int tid = threadIdx.x, wave = tid >> 6, lane = tid & 63;

    if (blockIdx.x >= 8) {
        const int tbl = blockIdx.x - 8;
        const float* part = (tbl == 0) ? partE : partS;
        for (int grp = wave; grp < 56; grp += 16) {
            float s = 0.f;
#pragma unroll
            for (int j = lane; j < BPB; j += 64) s += part[grp*BPB + j];
            s = wave_reduce_f(s);
            if (lane == 0) gg[grp] = s;
        }
        __syncthreads();
        if (tid == 0) {
            float tot = 0.f;
            for (int b = 0; b < NBATCH; ++b) {
                const float* G = gg + b * 14;
                int nv = 0;
                for (int c = 0; c < NB; ++c) nv += (G[8+c] > 0.f) ? 1 : 0;
                const float nvf = (float)((nv > 1) ? nv : 1);
                float pos = 0.f, neg = 0.f;
                for (int c = 0; c < NB; ++c) { pos += log1pf(G[c]); neg += log1pf(G[4+c]); }
                tot += pos / nvf + neg * 0.25f;
            }
            out[tbl] = CLW_C * tot * 0.25f;
            if (tbl == 0) {
                float bs = 0.f, be = 0.f;
                for (int b = 0; b < NBATCH; ++b) { bs += gg[b*14 + 12]; be += gg[b*14 + 13]; }
                out[2] = bs * (1.0f / 65536.0f);
                out[3] = be * (1.0f / 65536.0f);
            }
        }
        return;
    }

    const int a = blockIdx.x >> 2;   // 0 = S, 1 = E
    const int b = blockIdx.x & 3;
    const float* p = (a ? pE : pS) + (size_t)b * NLL;
    float* o = out + 4 + (size_t)a * (NBATCH * NLL) + (size_t)b * NLL;

    int asum = attn[b*LSEQ + lane] + attn[b*LSEQ + 64 + lane];
#pragma unroll
    for (int s = 1; s < 64; s <<= 1) asum += __shfl_xor(asum, s);
    const int mask_len = asum - 2;
    int k = (int)((float)mask_len * 0.3f);
    k = (k > 10) ? k : 10;
    const int ml2 = mask_len * mask_len;
    k = (k < ml2) ? k : ml2;

    for (int j = tid; j < NLL; j += 1024) sh[j] = __float_as_uint(p[j]);
    __syncthreads();

    unsigned lo = 0u, hi = 0x3F800000u;   // p in [0,1] -> bits <= 0x3F800000
    for (int it = 0; it < 32; ++it) {
        if (lo >= hi) break;                       // uniform across block
        const unsigned span = hi - lo;
        const unsigned mid = lo + (span >> 1) + (span & 1u);   // ceil midpoint, > lo
        int c = 0;
        for (int j = tid; j < NLL; j += 1024) c += (sh[j] >= mid) ? 1 : 0;
#pragma unroll
        for (int s = 1; s < 64; s <<= 1) c += __shfl_xor(c, s);
        if (lane == 0) csum[wave] = c;
        __syncthreads();
        int tot = 0;
#pragma unroll
        for (int w = 0; w < 16; ++w) tot += csum[w];
        if (tot >= k) lo = mid; else hi = mid - 1u;
        __syncthreads();
    }

    for (int j = tid; j < NLL; j += 1024) o[j] = (sh[j] >= lo) ? 1.0f : 0.0f;
}

extern "C" void kernel_launch(void* const* d_in, const int* in_sizes, int n_in,
                              void* d_out, int out_size, void* d_ws, size_t ws_size,
                              hipStream_t stream)
{
    const float* table_edge  = (const float*)d_in[0];
    const float* table_senti = (const float*)d_in[1];
    const int*   attn        = (const int*)d_in[2];
    const int*   tlabS       = (const int*)d_in[3];
    const int*   tlabE       = (const int*)d_in[4];
    const int*   lab_edge    = (const int*)d_in[5];
    const int*   lab_senti   = (const int*)d_in[6];
    const float* prox_edge   = (const float*)d_in[7];
    const float* prox_senti  = (const float*)d_in[8];
    const float* w_S         = (const float*)d_in[9];
    const float* b_S         = (const float*)d_in[10];
    const float* w_E         = (const float*)d_in[11];
    const float* b_E         = (const float*)d_in[12];

    float* out   = (float*)d_out;
    float* ws    = (float*)d_ws;
    float* pS    = ws;                      // 65536
    float* pE    = ws + 65536;              // 65536
    float* partE = ws + 131072;             // 4*14*512 = 28672
    float* partS = partE + 28672;           // 28672

    fused_pass<<<4096, 256, 0, stream>>>(table_edge, table_senti,
        lab_edge, lab_senti, attn, prox_edge, prox_senti,
        w_S, b_S, w_E, b_E, tlabS, tlabE, pS, pE, partE, partS);
    tail_k<<<10, 1024, 0, stream>>>(pS, pE, attn, partE, partS, out);
}